// Round 8
// baseline (3579.948 us; speedup 1.0000x reference)
//
#include <hip/hip_runtime.h>

// Problem constants (fixed by setup_inputs): im0 [B,C,H,W] fp32,
// flow [B,H,W,2] fp32, out [B,C,H,W] fp32.
constexpr int B_ = 4;
constexpr int C_ = 3;
constexpr int H_ = 1024;
constexpr int W_ = 1920;
constexpr int HW_ = H_ * W_;

// R8: direct global-atomic splat. R7's ablation proved the LDS-tile design
// is 100% bound on ds_add_f32 execution (~3.3 cyc/lane-op/CU, 502us for
// 94.4M lane-ops; loads+VALU alone = ~55us). TCC (global) atomics measured
// ~3x faster per lane-op in R0's flush. So: no LDS accumulator at all --
// each block owns a 64x64 pixel tile, reads flow/im0 with float4 quad
// loads, and fires the 12 bilinear-corner adds (4 corners x 3 channels)
// straight at out with unsafeAtomicAdd. Every splat is handled exactly
// once, anywhere in the image -> no near/far partition, no halo overscan
// (FETCH 200->160MB), no flush. out is zeroed first (atomic accumulation).
// Blocks are XCD-chunk swizzled (1920 tiles = 8 x 240, bijective) so each
// XCD's in-flight atomic destinations stay in its 4MB L2.
constexpr int TW = 64;
constexpr int TH = 64;
constexpr int NTHR = 256;
constexpr int TILES_X = W_ / TW;              // 30
constexpr int TILES_Y = H_ / TH;              // 16
constexpr int TILES_PER_IM = TILES_X * TILES_Y;   // 480
constexpr int NTILES = TILES_PER_IM * B_;     // 1920 (divisible by 8 XCDs)
constexpr int QPB = (TW * TH) / 4;            // 1024 quads per block
constexpr int QPT = QPB / NTHR;               // 4 quads per thread

static_assert(W_ % TW == 0 && H_ % TH == 0, "exact tiling assumed");
static_assert(W_ % 4 == 0, "quad alignment assumed");
static_assert(NTILES % 8 == 0, "simple XCD swizzle requires nwg % 8 == 0");

__global__ __launch_bounds__(NTHR) void fw_splat(
    const float* __restrict__ im0,
    const float2* __restrict__ flow,
    const int* __restrict__ mode_p,
    float* __restrict__ out) {
    // XCD-chunk swizzle: hardware round-robins consecutive flat ids across
    // the 8 XCDs; remap so XCD j gets the contiguous tile chunk
    // [j*240, (j+1)*240) -> its atomic working set is an ~4MB band (L2-fit).
    const int flat = blockIdx.x;
    const int sw = (flat & 7) * (NTILES / 8) + (flat >> 3);
    const int b    = sw / TILES_PER_IM;
    const int rem  = sw - b * TILES_PER_IM;
    const int ty0  = (rem / TILES_X) * TH;
    const int tx0  = (rem % TILES_X) * TW;

    const int mode = *mode_p;                  // wave-uniform

    const float*  im0b  = im0  + (size_t)b * C_ * HW_;
    const float2* flowb = flow + (size_t)b * HW_;
    float*        outb  = out  + (size_t)b * C_ * HW_;

#pragma unroll
    for (int k = 0; k < QPT; ++k) {
        const int qq = threadIdx.x + NTHR * k; // consecutive lanes -> adjacent quads
        const int qy = qq >> 4;                // 16 quads per 64-px row
        const int qx = (qq & 15) * 4;
        const int gy = ty0 + qy;
        const int gx = tx0 + qx;

        const int src = gy * W_ + gx;          // multiple of 4
        const float4 f01 = reinterpret_cast<const float4*>(flowb)[src >> 1];
        const float4 f23 = reinterpret_cast<const float4*>(flowb)[(src >> 1) + 1];
        const float4 sA  = reinterpret_cast<const float4*>(im0b)[src >> 2];
        const float4 sB  = reinterpret_cast<const float4*>(im0b + HW_)[src >> 2];
        const float4 sC  = reinterpret_cast<const float4*>(im0b + 2 * HW_)[src >> 2];

        const float fx[4] = { f01.x, f01.z, f23.x, f23.z };
        const float fy[4] = { f01.y, f01.w, f23.y, f23.w };
        const float s0[4] = { sA.x, sA.y, sA.z, sA.w };
        const float s1[4] = { sB.x, sB.y, sB.z, sB.w };
        const float s2[4] = { sC.x, sC.y, sC.z, sC.w };

        if (mode == 1) {                       // nearest: 1 corner, weight 1
#pragma unroll
            for (int i = 0; i < 4; ++i) {
                const int gxi = gx + i;
                const int cx = (int)rintf((float)gxi + fx[i]);
                const int cy = (int)rintf((float)gy  + fy[i]);
                if ((unsigned)cx < (unsigned)W_ && (unsigned)cy < (unsigned)H_) {
                    const int dsti = cy * W_ + cx;
                    unsafeAtomicAdd(outb + dsti,           s0[i]);
                    unsafeAtomicAdd(outb + HW_ + dsti,     s1[i]);
                    unsafeAtomicAdd(outb + 2 * HW_ + dsti, s2[i]);
                }
            }
        } else {                               // bilinear: 4 corners x 3 ch
#pragma unroll
            for (int i = 0; i < 4; ++i) {
                const int gxi = gx + i;
                const float px = (float)gxi + fx[i];
                const float py = (float)gy  + fy[i];
                const float xf = floorf(px), yf = floorf(py);
                const int x0 = (int)xf, y0 = (int)yf;
                const float wx1 = px - xf, wy1 = py - yf;
                const float wx0 = 1.0f - wx1, wy0 = 1.0f - wy1;

                const int   cxs[4] = { x0, x0 + 1, x0,     x0 + 1 };
                const int   cys[4] = { y0, y0,     y0 + 1, y0 + 1 };
                const float cws[4] = { wx0 * wy0, wx1 * wy0,
                                       wx0 * wy1, wx1 * wy1 };
#pragma unroll
                for (int c = 0; c < 4; ++c) {
                    if ((unsigned)cxs[c] < (unsigned)W_ &&
                        (unsigned)cys[c] < (unsigned)H_) {
                        const int dsti = cys[c] * W_ + cxs[c];
                        const float w = cws[c];
                        unsafeAtomicAdd(outb + dsti,           s0[i] * w);
                        unsafeAtomicAdd(outb + HW_ + dsti,     s1[i] * w);
                        unsafeAtomicAdd(outb + 2 * HW_ + dsti, s2[i] * w);
                    }
                }
            }
        }
    }
}

extern "C" void kernel_launch(void* const* d_in, const int* in_sizes, int n_in,
                              void* d_out, int out_size, void* d_ws, size_t ws_size,
                              hipStream_t stream) {
    const float*  im0  = (const float*)d_in[0];
    const float2* flow = (const float2*)d_in[1];
    // d_in[2] = flowback (unused by the forward splat)
    const int*    mode = (const int*)d_in[3];
    float* out = (float*)d_out;

    // Output accumulates via atomics -> zero it (harness poisons d_out).
    (void)hipMemsetAsync(d_out, 0, (size_t)out_size * sizeof(float), stream);

    fw_splat<<<dim3(NTILES), dim3(NTHR), 0, stream>>>(im0, flow, mode, out);
}